// Round 1
// baseline (27318.542 us; speedup 1.0000x reference)
//
#include <hip/hip_runtime.h>

// StackedMatchLSTM on MI355X.
// B=32, TP=512, TQ=64, DP=DQ=H=AH=256, NL=2.
// Decomposition:
//   per layer: xpl[b,t,:] = xt @ [W_att_p | W_lstm_x]   (parallel GEMM, N=1280)
//              qv[b,tq,:] = input_q @ [W_att_q | W_lstm_z]  (parallel GEMM)
//   scan (sequential over t, one workgroup per batch):
//              hw = h @ [W_att_r | W_lstm_h]
//              s[tq] = sum_a tanh(qv[tq,a] + xpl[t,a] + hw[a]) * w_att[a]
//              alpha = softmax(mask ? s : -1e9)
//              pre[j] = xpl[t,256+j] + hw[256+j] + sum_tq alpha[tq]*qv[tq,256+j] + bias[j]
//              LSTM gates -> h,c update, write h.

#define NB 32
#define TPL 512
#define TQL 64
#define DD 256      // DP = DQ = H = AH
#define H4 1024     // 4*H
#define NC 1280     // AH + 4H

__device__ __forceinline__ float fast_tanh(float x) {
  float xc = fminf(fmaxf(x, -9.f), 9.f);
  float e = __expf(2.f * xc);
  return (e - 1.f) * __builtin_amdgcn_rcpf(e + 1.f);
}
__device__ __forceinline__ float fast_sigmoid(float x) {
  return __builtin_amdgcn_rcpf(1.f + __expf(-x));
}

// Pack the three K=256 weight blocks into [256][1280] row-major arrays per layer.
__global__ __launch_bounds__(256) void pack_weights(
    const float* __restrict__ Wp, const float* __restrict__ Wq,
    const float* __restrict__ Wr, const float* __restrict__ Wl,
    float* __restrict__ wx, float* __restrict__ wqv, float* __restrict__ wh)
{
  int d = blockIdx.y;
  int idx = blockIdx.x * 256 + threadIdx.x;
  if (idx >= DD * NC) return;
  int k = idx / NC, j = idx % NC;
  int o = d * DD * NC + idx;
  const float* Wld = Wl + (size_t)d * 768 * H4;
  if (j < DD) {
    int s = d * DD * DD + k * DD + j;
    wx[o] = Wp[s]; wqv[o] = Wq[s]; wh[o] = Wr[s];
  } else {
    int c = j - DD;
    wx[o]  = Wld[(size_t)k * H4 + c];            // rows 0..255   (x part)
    wqv[o] = Wld[(size_t)(DD + k) * H4 + c];     // rows 256..511 (z part)
    wh[o]  = Wld[(size_t)(2 * DD + k) * H4 + c]; // rows 512..767 (h part)
  }
}

// C[M][1280] = A[M][256] @ B[256][1280], fp32, M % 64 == 0.
__global__ __launch_bounds__(256) void sgemm(
    const float* __restrict__ A, const float* __restrict__ Bm,
    float* __restrict__ C)
{
  __shared__ float As[16][65];   // +1 pad: avoids 16-way write conflict
  __shared__ float Bs[16][64];
  int tid = threadIdx.x;
  int tx = tid & 15, ty = tid >> 4;
  int col0 = blockIdx.x * 64, row0 = blockIdx.y * 64;
  float acc[4][4] = {};
  for (int kt = 0; kt < DD; kt += 16) {
    #pragma unroll
    for (int i = 0; i < 4; ++i) {
      int e = tid + i * 256;
      As[e & 15][e >> 4] = A[(size_t)(row0 + (e >> 4)) * DD + kt + (e & 15)];
      Bs[e >> 6][e & 63] = Bm[(size_t)(kt + (e >> 6)) * NC + col0 + (e & 63)];
    }
    __syncthreads();
    #pragma unroll
    for (int kk = 0; kk < 16; ++kk) {
      float a[4], bv[4];
      #pragma unroll
      for (int i = 0; i < 4; ++i) a[i] = As[kk][ty * 4 + i];
      #pragma unroll
      for (int j = 0; j < 4; ++j) bv[j] = Bs[kk][tx * 4 + j];
      #pragma unroll
      for (int i = 0; i < 4; ++i)
        #pragma unroll
        for (int j = 0; j < 4; ++j)
          acc[i][j] = fmaf(a[i], bv[j], acc[i][j]);
    }
    __syncthreads();
  }
  #pragma unroll
  for (int i = 0; i < 4; ++i)
    #pragma unroll
    for (int j = 0; j < 4; ++j)
      C[(size_t)(row0 + ty * 4 + i) * NC + col0 + tx * 4 + j] = acc[i][j];
}

// One workgroup (640 threads = 10 waves) per batch element; loops over TP steps.
__global__ __launch_bounds__(640) void scan(
    const float* __restrict__ xpl,    // [NB*TP][NC]
    const float* __restrict__ qv,     // [NB*TQ][NC]  (qWq | Vl)
    const float* __restrict__ wh,     // [256][NC]    (W_att_r | Wl_h)
    const float* __restrict__ wa,     // [256]
    const float* __restrict__ bias_f, // [256]
    const float* __restrict__ bias_iog, // [768]
    const float* __restrict__ mask_p, // [NB*TP]
    const float* __restrict__ mask_q, // [NB*TQ]
    float* __restrict__ out)          // [NB*TP][256]
{
  int b = blockIdx.x;
  int tid = threadIdx.x;
  int lane = tid & 63, wave = tid >> 6;

  __shared__ float h_s[DD], c_s[DD];
  __shared__ float hw[NC];
  __shared__ float sc[TQL], al[TQL];
  __shared__ float pre[H4];

  for (int j = tid; j < DD; j += 640) { h_s[j] = 0.f; c_s[j] = 0.f; }
  __syncthreads();

  const float* qvb = qv + (size_t)b * TQL * NC;
  const float2* whp = (const float2*)wh + tid;          // columns 2*tid, 2*tid+1
  const float2* vlp = (const float2*)(qvb + DD) + tid;  // Vl columns (valid tid<512)

  for (int t = 0; t < TPL; ++t) {
    const float* xrow = xpl + ((size_t)b * TPL + t) * NC;

    // P1: hw[j] = sum_k h[k] * wh[k][j]   (K=256, N=1280; 2 cols/thread)
    {
      float ax = 0.f, ay = 0.f;
      #pragma unroll 8
      for (int k = 0; k < DD; ++k) {
        float hk = h_s[k];
        float2 w = whp[k * (NC / 2)];
        ax = fmaf(hk, w.x, ax);
        ay = fmaf(hk, w.y, ay);
      }
      hw[2 * tid] = ax; hw[2 * tid + 1] = ay;
    }
    __syncthreads();

    // P2: attention scores s[tq] (wave per row, 10 waves over 64 rows)
    for (int tq = wave; tq < TQL; tq += 10) {
      const float* qrow = qvb + (size_t)tq * NC;
      float part = 0.f;
      #pragma unroll
      for (int ai = 0; ai < 4; ++ai) {
        int a = lane + ai * 64;
        part = fmaf(fast_tanh(qrow[a] + xrow[a] + hw[a]), wa[a], part);
      }
      #pragma unroll
      for (int off = 32; off > 0; off >>= 1) part += __shfl_xor(part, off);
      if (lane == 0) sc[tq] = part;
    }
    __syncthreads();

    // P3: softmax over TQ=64 (wave 0)
    if (wave == 0) {
      float v = (mask_q[b * TQL + lane] > 0.f) ? sc[lane] : -1e9f;
      float m = v;
      #pragma unroll
      for (int off = 32; off > 0; off >>= 1) m = fmaxf(m, __shfl_xor(m, off));
      float p = __expf(v - m);
      float s = p;
      #pragma unroll
      for (int off = 32; off > 0; off >>= 1) s += __shfl_xor(s, off);
      al[lane] = p * __builtin_amdgcn_rcpf(s);
    }
    __syncthreads();

    // P4: pre[j] = alpha@Vl + hw[256+j] + xrow[256+j] + bias[j]  (threads 0..511)
    if (tid < 512) {
      int j = 2 * tid;
      float ax = 0.f, ay = 0.f;
      #pragma unroll 8
      for (int tq = 0; tq < TQL; ++tq) {
        float a0 = al[tq];
        float2 v = vlp[tq * (NC / 2)];
        ax = fmaf(a0, v.x, ax);
        ay = fmaf(a0, v.y, ay);
      }
      float b0 = (j < DD) ? bias_f[j] : bias_iog[j - DD];
      float b1 = (j + 1 < DD) ? bias_f[j + 1] : bias_iog[j + 1 - DD];
      pre[j]     = ax + hw[DD + j]     + xrow[DD + j]     + b0;
      pre[j + 1] = ay + hw[DD + j + 1] + xrow[DD + j + 1] + b1;
    }
    __syncthreads();

    // P5: LSTM gates + state update (threads 0..255)
    if (tid < DD) {
      float f  = pre[tid];
      float ii = pre[DD + tid];
      float oo = pre[2 * DD + tid];
      float g  = pre[3 * DD + tid];
      float mt = mask_p[b * TPL + t];
      float c0 = c_s[tid], h0 = h_s[tid];
      float c1 = fast_sigmoid(f) * c0 + fast_sigmoid(ii) * fast_tanh(g);
      c1 = c1 * mt + c0 * (1.f - mt);
      float h1 = fast_sigmoid(oo) * fast_tanh(c1);
      h1 = h1 * mt + h0 * (1.f - mt);
      c_s[tid] = c1; h_s[tid] = h1;
      out[((size_t)b * TPL + t) * DD + tid] = h1;
    }
    __syncthreads();
  }
}

extern "C" void kernel_launch(void* const* d_in, const int* in_sizes, int n_in,
                              void* d_out, int out_size, void* d_ws, size_t ws_size,
                              hipStream_t stream) {
  const float* input_p  = (const float*)d_in[0];
  const float* mask_p   = (const float*)d_in[1];
  const float* input_q  = (const float*)d_in[2];
  const float* mask_q   = (const float*)d_in[3];
  const float* W_att_p  = (const float*)d_in[4];
  const float* W_att_q  = (const float*)d_in[5];
  const float* W_att_r  = (const float*)d_in[6];
  const float* w_att    = (const float*)d_in[7];
  const float* W_lstm   = (const float*)d_in[8];
  const float* bias_f   = (const float*)d_in[9];
  const float* bias_iog = (const float*)d_in[10];
  float* out = (float*)d_out;
  float* ws  = (float*)d_ws;

  const size_t SZ_XPL = (size_t)NB * TPL * NC;  // 20,971,520 floats (reused per layer)
  const size_t SZ_QV  = (size_t)NB * TQL * NC;  //  2,621,440 per layer
  const size_t SZ_W   = (size_t)DD * NC;        //    327,680 per layer

  float* ws_xpl = ws;
  float* ws_qv  = ws_xpl + SZ_XPL;
  float* ws_wx  = ws_qv  + 2 * SZ_QV;
  float* ws_wqv = ws_wx  + 2 * SZ_W;
  float* ws_wh  = ws_wqv + 2 * SZ_W;
  float* ws_o0  = ws_wh  + 2 * SZ_W;            // + 4,194,304 -> ~129.5 MB total
  (void)ws_size; (void)in_sizes; (void)n_in; (void)out_size;

  dim3 gpack((DD * NC + 255) / 256, 2);
  pack_weights<<<gpack, 256, 0, stream>>>(W_att_p, W_att_q, W_att_r, W_lstm,
                                          ws_wx, ws_wqv, ws_wh);

  // qv for both layers (depends only on input_q)
  for (int d = 0; d < 2; ++d) {
    dim3 g(NC / 64, (NB * TQL) / 64);
    sgemm<<<g, 256, 0, stream>>>(input_q, ws_wqv + d * SZ_W, ws_qv + d * SZ_QV);
  }

  // layer 0
  {
    dim3 g(NC / 64, (NB * TPL) / 64);
    sgemm<<<g, 256, 0, stream>>>(input_p, ws_wx, ws_xpl);
    scan<<<NB, 640, 0, stream>>>(ws_xpl, ws_qv, ws_wh, w_att, bias_f, bias_iog,
                                 mask_p, mask_q, ws_o0);
  }
  // layer 1
  {
    dim3 g(NC / 64, (NB * TPL) / 64);
    sgemm<<<g, 256, 0, stream>>>(ws_o0, ws_wx + SZ_W, ws_xpl);
    scan<<<NB, 640, 0, stream>>>(ws_xpl, ws_qv + SZ_QV, ws_wh + SZ_W,
                                 w_att + DD, bias_f + DD, bias_iog + 3 * DD,
                                 mask_p, mask_q, out);
  }
}

// Round 2
// 26923.837 us; speedup vs baseline: 1.0147x; 1.0147x over previous
//
#include <hip/hip_runtime.h>
#include <hip/hip_bf16.h>

// StackedMatchLSTM on MI355X.
// B=32, TP=512, TQ=64, DP=DQ=H=AH=256, NL=2.
//   per layer: xpl[b,t,:] = xt @ [W_att_p | W_lstm_x]       (fp32 GEMM, N=1280)
//              qv[b,tq,:] = input_q @ [W_att_q | W_lstm_z]  (fp32 GEMM)
//              vl_bf      = bf16(qv[:,:,256:1280])          (streamed every step)
//              wh_bf      = bf16([W_att_r | W_lstm_h])      (streamed every step)
//   scan: one WG (640 thr) per batch, sequential over t.

#define NB 32
#define TPL 512
#define TQL 64
#define DD 256      // DP = DQ = H = AH
#define H4 1024     // 4*H
#define NC 1280     // AH + 4H

__device__ __forceinline__ float fast_tanh(float x) {
  float xc = fminf(fmaxf(x, -9.f), 9.f);
  float e = __expf(2.f * xc);
  return (e - 1.f) * __builtin_amdgcn_rcpf(e + 1.f);
}
__device__ __forceinline__ float fast_sigmoid(float x) {
  return __builtin_amdgcn_rcpf(1.f + __expf(-x));
}
__device__ __forceinline__ float bflo(unsigned int w) {  // low ushort -> f32
  return __uint_as_float(w << 16);
}
__device__ __forceinline__ float bfhi(unsigned int w) {  // high ushort -> f32
  return __uint_as_float(w & 0xffff0000u);
}

// Pack weights: wx, wqv fp32 [256][1280] (GEMM B-matrices); wh bf16 [256][1280].
__global__ __launch_bounds__(256) void pack_weights(
    const float* __restrict__ Wp, const float* __restrict__ Wq,
    const float* __restrict__ Wr, const float* __restrict__ Wl,
    float* __restrict__ wx, float* __restrict__ wqv,
    unsigned short* __restrict__ wh_bf)
{
  int d = blockIdx.y;
  int idx = blockIdx.x * 256 + threadIdx.x;
  if (idx >= DD * NC) return;
  int k = idx / NC, j = idx % NC;
  int o = d * DD * NC + idx;
  const float* Wld = Wl + (size_t)d * 768 * H4;
  float vx, vq, vh;
  if (j < DD) {
    int s = d * DD * DD + k * DD + j;
    vx = Wp[s]; vq = Wq[s]; vh = Wr[s];
  } else {
    int c = j - DD;
    vx = Wld[(size_t)k * H4 + c];
    vq = Wld[(size_t)(DD + k) * H4 + c];
    vh = Wld[(size_t)(2 * DD + k) * H4 + c];
  }
  wx[o] = vx; wqv[o] = vq;
  wh_bf[o] = __hip_bfloat16_raw(__float2bfloat16(vh)).x;
}

// vl_bf[b*TQ+tq][c] = bf16(qv[b*TQ+tq][256+c]), c in [0,1024)
__global__ __launch_bounds__(256) void cvt_vl(
    const float* __restrict__ qv, unsigned short* __restrict__ vl_bf)
{
  int idx = blockIdx.x * 256 + threadIdx.x;          // over NB*TQL*H4
  int r = idx >> 10, c = idx & 1023;
  float v = qv[(size_t)r * NC + DD + c];
  vl_bf[idx] = __hip_bfloat16_raw(__float2bfloat16(v)).x;
}

// C[M][1280] = A[M][256] @ B[256][1280], fp32, M % 64 == 0.
__global__ __launch_bounds__(256) void sgemm(
    const float* __restrict__ A, const float* __restrict__ Bm,
    float* __restrict__ C)
{
  __shared__ float As[16][65];
  __shared__ float Bs[16][64];
  int tid = threadIdx.x;
  int tx = tid & 15, ty = tid >> 4;
  int col0 = blockIdx.x * 64, row0 = blockIdx.y * 64;
  float acc[4][4] = {};
  for (int kt = 0; kt < DD; kt += 16) {
    #pragma unroll
    for (int i = 0; i < 4; ++i) {
      int e = tid + i * 256;
      As[e & 15][e >> 4] = A[(size_t)(row0 + (e >> 4)) * DD + kt + (e & 15)];
      Bs[e >> 6][e & 63] = Bm[(size_t)(kt + (e >> 6)) * NC + col0 + (e & 63)];
    }
    __syncthreads();
    #pragma unroll
    for (int kk = 0; kk < 16; ++kk) {
      float a[4], bv[4];
      #pragma unroll
      for (int i = 0; i < 4; ++i) a[i] = As[kk][ty * 4 + i];
      #pragma unroll
      for (int j = 0; j < 4; ++j) bv[j] = Bs[kk][tx * 4 + j];
      #pragma unroll
      for (int i = 0; i < 4; ++i)
        #pragma unroll
        for (int j = 0; j < 4; ++j)
          acc[i][j] = fmaf(a[i], bv[j], acc[i][j]);
    }
    __syncthreads();
  }
  #pragma unroll
  for (int i = 0; i < 4; ++i)
    #pragma unroll
    for (int j = 0; j < 4; ++j)
      C[(size_t)(row0 + ty * 4 + i) * NC + col0 + tx * 4 + j] = acc[i][j];
}

// One workgroup (640 threads = 10 waves) per batch element; loops over TP steps.
__global__ __launch_bounds__(640) void scan(
    const float* __restrict__ xpl,            // [NB*TP][NC] fp32
    const float* __restrict__ qv,             // [NB*TQ][NC] fp32 (attn cols read)
    const unsigned short* __restrict__ vl_bf, // [NB*TQ][1024] bf16
    const unsigned short* __restrict__ wh_bf, // [256][1280] bf16
    const float* __restrict__ wa,             // [256]
    const float* __restrict__ bias_f,         // [256]
    const float* __restrict__ bias_iog,       // [768]
    const float* __restrict__ mask_p,         // [NB*TP]
    const float* __restrict__ mask_q,         // [NB*TQ]
    float* __restrict__ out)                  // [NB*TP][256]
{
  int b = blockIdx.x;
  int tid = threadIdx.x;
  int lane = tid & 63, wave = tid >> 6;

  __shared__ float h_s[DD], c_s[DD];
  __shared__ float hw[NC];
  __shared__ float sc[TQL];
  __shared__ float pre[H4];
  __shared__ float wa_s[DD];
  __shared__ float bias_s[H4];

  for (int j = tid; j < DD; j += 640) { h_s[j] = 0.f; c_s[j] = 0.f; wa_s[j] = wa[j]; }
  for (int j = tid; j < H4; j += 640)
    bias_s[j] = (j < DD) ? bias_f[j] : bias_iog[j - DD];
  __syncthreads();

  const float* qvb = qv + (size_t)b * TQL * NC;
  const unsigned int* whu = (const unsigned int*)wh_bf + tid;      // cols 2tid,2tid+1
  const unsigned int* vlu = (const unsigned int*)(vl_bf + (size_t)b * TQL * H4) + tid;
  float mq0 = (tid < TQL) ? mask_q[b * TQL + tid] : 0.f;           // only lane's own used
  float mqw = mask_q[b * TQL + lane];                              // per-wave softmax mask
  (void)mq0;

  for (int t = 0; t < TPL; ++t) {
    const float* xrow = xpl + ((size_t)b * TPL + t) * NC;

    // P1: hw[j] = sum_k h[k] * wh[k][j]   (bf16 weights, 2 cols/thread)
    {
      float ax = 0.f, ay = 0.f;
      #pragma unroll 16
      for (int k = 0; k < DD; ++k) {
        unsigned int w = __builtin_nontemporal_load(&whu[k * (NC / 2)]);
        float hk = h_s[k];
        ax = fmaf(hk, bflo(w), ax);
        ay = fmaf(hk, bfhi(w), ay);
      }
      hw[2 * tid] = ax; hw[2 * tid + 1] = ay;
    }
    __syncthreads();

    // P2: attention scores s[tq] (wave per row, 10 waves over 64 rows)
    for (int tq = wave; tq < TQL; tq += 10) {
      const float* qrow = qvb + (size_t)tq * NC;
      float part = 0.f;
      #pragma unroll
      for (int ai = 0; ai < 4; ++ai) {
        int a = lane + ai * 64;
        part = fmaf(fast_tanh(qrow[a] + xrow[a] + hw[a]), wa_s[a], part);
      }
      #pragma unroll
      for (int off = 32; off > 0; off >>= 1) part += __shfl_xor(part, off);
      if (lane == 0) sc[tq] = part;
    }
    __syncthreads();

    // P3+P4 fused: per-wave softmax (redundant in waves 0..7), then pre[].
    if (tid < 512) {
      float v = (mqw > 0.f) ? sc[lane] : -1e9f;
      float m = v;
      #pragma unroll
      for (int off = 32; off > 0; off >>= 1) m = fmaxf(m, __shfl_xor(m, off));
      float p = __expf(v - m);
      float s = p;
      #pragma unroll
      for (int off = 32; off > 0; off >>= 1) s += __shfl_xor(s, off);
      float al_reg = p * __builtin_amdgcn_rcpf(s);   // alpha[lane] in-register

      int j = 2 * tid;
      float ax = 0.f, ay = 0.f;
      #pragma unroll 16
      for (int tq = 0; tq < TQL; ++tq) {
        unsigned int v2 = __builtin_nontemporal_load(&vlu[tq * (H4 / 2)]);
        float a0 = __shfl(al_reg, tq);
        ax = fmaf(a0, bflo(v2), ax);
        ay = fmaf(a0, bfhi(v2), ay);
      }
      pre[j]     = ax + hw[DD + j]     + xrow[DD + j]     + bias_s[j];
      pre[j + 1] = ay + hw[DD + j + 1] + xrow[DD + j + 1] + bias_s[j + 1];
    }
    __syncthreads();

    // P5: LSTM gates + state update (threads 0..255)
    if (tid < DD) {
      float f  = pre[tid];
      float ii = pre[DD + tid];
      float oo = pre[2 * DD + tid];
      float g  = pre[3 * DD + tid];
      float mt = mask_p[b * TPL + t];
      float c0 = c_s[tid], h0 = h_s[tid];
      float c1 = fast_sigmoid(f) * c0 + fast_sigmoid(ii) * fast_tanh(g);
      c1 = c1 * mt + c0 * (1.f - mt);
      float h1 = fast_sigmoid(oo) * fast_tanh(c1);
      h1 = h1 * mt + h0 * (1.f - mt);
      c_s[tid] = c1; h_s[tid] = h1;
      out[((size_t)b * TPL + t) * DD + tid] = h1;
    }
    __syncthreads();
  }
}

extern "C" void kernel_launch(void* const* d_in, const int* in_sizes, int n_in,
                              void* d_out, int out_size, void* d_ws, size_t ws_size,
                              hipStream_t stream) {
  const float* input_p  = (const float*)d_in[0];
  const float* mask_p   = (const float*)d_in[1];
  const float* input_q  = (const float*)d_in[2];
  const float* mask_q   = (const float*)d_in[3];
  const float* W_att_p  = (const float*)d_in[4];
  const float* W_att_q  = (const float*)d_in[5];
  const float* W_att_r  = (const float*)d_in[6];
  const float* w_att    = (const float*)d_in[7];
  const float* W_lstm   = (const float*)d_in[8];
  const float* bias_f   = (const float*)d_in[9];
  const float* bias_iog = (const float*)d_in[10];
  float* out = (float*)d_out;
  float* ws  = (float*)d_ws;

  const size_t SZ_XPL = (size_t)NB * TPL * NC;   // 20,971,520 f
  const size_t SZ_QV  = (size_t)NB * TQL * NC;   //  2,621,440 f per layer
  const size_t SZ_W   = (size_t)DD * NC;         //    327,680 elems per layer
  const size_t SZ_VL  = (size_t)NB * TQL * H4;   //  2,097,152 ushorts per layer

  float* ws_xpl = ws;
  float* ws_qv  = ws_xpl + SZ_XPL;
  float* ws_wx  = ws_qv  + 2 * SZ_QV;
  float* ws_wqv = ws_wx  + 2 * SZ_W;
  float* ws_o0  = ws_wqv + 2 * SZ_W;
  unsigned short* ws_wh_bf = (unsigned short*)(ws_o0 + (size_t)NB * TPL * DD);
  unsigned short* ws_vl_bf = ws_wh_bf + 2 * SZ_W;
  // total ~ (20.97M + 5.24M + 0.66M + 0.66M + 4.19M) f + (0.66M + 4.19M) us  ~= 136 MB
  (void)ws_size; (void)in_sizes; (void)n_in; (void)out_size;

  dim3 gpack((DD * NC + 255) / 256, 2);
  pack_weights<<<gpack, 256, 0, stream>>>(W_att_p, W_att_q, W_att_r, W_lstm,
                                          ws_wx, ws_wqv, ws_wh_bf);

  for (int d = 0; d < 2; ++d) {
    dim3 g(NC / 64, (NB * TQL) / 64);
    sgemm<<<g, 256, 0, stream>>>(input_q, ws_wqv + d * SZ_W, ws_qv + d * SZ_QV);
    cvt_vl<<<(NB * TQL * H4) / 256, 256, 0, stream>>>(ws_qv + d * SZ_QV,
                                                      ws_vl_bf + d * SZ_VL);
  }

  // layer 0
  {
    dim3 g(NC / 64, (NB * TPL) / 64);
    sgemm<<<g, 256, 0, stream>>>(input_p, ws_wx, ws_xpl);
    scan<<<NB, 640, 0, stream>>>(ws_xpl, ws_qv, ws_vl_bf, ws_wh_bf,
                                 w_att, bias_f, bias_iog, mask_p, mask_q, ws_o0);
  }
  // layer 1
  {
    dim3 g(NC / 64, (NB * TPL) / 64);
    sgemm<<<g, 256, 0, stream>>>(ws_o0, ws_wx + SZ_W, ws_xpl);
    scan<<<NB, 640, 0, stream>>>(ws_xpl, ws_qv + SZ_QV, ws_vl_bf + SZ_VL,
                                 ws_wh_bf + SZ_W, w_att + DD, bias_f + DD,
                                 bias_iog + 3 * DD, mask_p, mask_q, out);
  }
}

// Round 3
// 11527.943 us; speedup vs baseline: 2.3698x; 2.3355x over previous
//
#include <hip/hip_runtime.h>
#include <hip/hip_bf16.h>

// StackedMatchLSTM on MI355X — multi-CU scan.
// B=32, TP=512, TQ=64, DP=DQ=H=AH=256, NL=2.
// Scan: 256 WGs = 8 slices x 32 batches. WG (b,j) owns:
//   - 32 attention cols [32j,32j+32) of hw = h @ [W_att_r]
//   - gate cols {f,i,o,g} x h-elems m in [32j,32j+32) of hw = h @ Wl_h
// Cross-WG per step: score partials (64 f) + h slices (32 f) via agent-scope
// atomics at the LLC (per-XCD L2 stays clean -> weights remain L2-cached).

#define NB 32
#define TPL 512
#define TQL 64
#define DD 256      // DP = DQ = H = AH
#define H4 1024     // 4*H
#define NC 1280     // AH + 4H
#define NS 8        // slices per batch
#define SC 160      // cols per slice = 32 att + 128 gate

__device__ __forceinline__ float fast_tanh(float x) {
  float xc = fminf(fmaxf(x, -9.f), 9.f);
  float e = __expf(2.f * xc);
  return (e - 1.f) * __builtin_amdgcn_rcpf(e + 1.f);
}
__device__ __forceinline__ float fast_sigmoid(float x) {
  return __builtin_amdgcn_rcpf(1.f + __expf(-x));
}
__device__ __forceinline__ float bflo(unsigned int w) { return __uint_as_float(w << 16); }
__device__ __forceinline__ float bfhi(unsigned int w) { return __uint_as_float(w & 0xffff0000u); }
__device__ __forceinline__ unsigned int packbf(float a, float b) {
  unsigned int lo = __hip_bfloat16_raw(__float2bfloat16(a)).x;
  unsigned int hi = __hip_bfloat16_raw(__float2bfloat16(b)).x;
  return lo | (hi << 16);
}

// ---- agent-scope (cross-XCD coherent) helpers -------------------------------
__device__ __forceinline__ float aloadf(const float* p) {
  return __hip_atomic_load(p, __ATOMIC_RELAXED, __HIP_MEMORY_SCOPE_AGENT);
}
__device__ __forceinline__ void astoref(float* p, float v) {
  __hip_atomic_store(p, v, __ATOMIC_RELAXED, __HIP_MEMORY_SCOPE_AGENT);
}
__device__ __forceinline__ void radd(int* p) {
  __hip_atomic_fetch_add(p, 1, __ATOMIC_RELEASE, __HIP_MEMORY_SCOPE_AGENT);
}
__device__ __forceinline__ void spin_ge(int* p, int tgt) {
  int guard = 0;
  // RMW(+0) always reads at the coherence point — stale-L2-proof.
  while (__hip_atomic_fetch_add(p, 0, __ATOMIC_RELAXED, __HIP_MEMORY_SCOPE_AGENT) < tgt) {
    __builtin_amdgcn_s_sleep(1);
    if (++guard > (1 << 26)) break;   // bail out instead of hanging the harness
  }
}

// permuted xpl column layout: slice-major, per slice: 32 att | f32 | i32 | o32 | g32
__device__ __forceinline__ int perm_col(int c) {
  if (c < DD) return (c >> 5) * SC + (c & 31);
  int cc = c - DD;            // 0..1023
  int g = cc >> 8;            // 0..3 = f,i,o,g
  int m = cc & 255;
  return (m >> 5) * SC + 32 + (g << 5) + (m & 31);
}

// ---- weight prep ------------------------------------------------------------
// wx  = [Wp | Wl_x]  fp32 [256][1280]  (sgemm B for xpl)
// wqv = [Wq | Wl_z]  fp32 [256][1280]  (sgemm B for qv)
__global__ __launch_bounds__(256) void pack_weights(
    const float* __restrict__ Wp, const float* __restrict__ Wq,
    const float* __restrict__ Wl,
    float* __restrict__ wx, float* __restrict__ wqv)
{
  int d = blockIdx.y;
  int idx = blockIdx.x * 256 + threadIdx.x;
  if (idx >= DD * NC) return;
  int k = idx / NC, j = idx % NC;
  int o = d * DD * NC + idx;
  const float* Wld = Wl + (size_t)d * 768 * H4;
  if (j < DD) {
    int s = d * DD * DD + k * DD + j;
    wx[o] = Wp[s]; wqv[o] = Wq[s];
  } else {
    int c = j - DD;
    wx[o]  = Wld[(size_t)k * H4 + c];
    wqv[o] = Wld[(size_t)(DD + k) * H4 + c];
  }
}

// whs: bf16 slices. uint2 per (d,j,kq,pos) = 4 consecutive k of one column.
// flat index: ((d*8 + j)*64 + kq)*160 + pos
__global__ __launch_bounds__(256) void pack_whs(
    const float* __restrict__ Wr, const float* __restrict__ Wl,
    uint2* __restrict__ whs)
{
  int idx = blockIdx.x * 256 + threadIdx.x;
  if (idx >= 2 * NS * 64 * SC) return;
  int pos = idx % SC; int r = idx / SC;
  int kq = r % 64; r /= 64;
  int j = r % NS; int d = r / NS;
  float v[4];
  #pragma unroll
  for (int kr = 0; kr < 4; ++kr) {
    int k = kq * 4 + kr;
    float x;
    if (pos < 32) {
      x = Wr[((size_t)d * DD + k) * DD + j * 32 + pos];          // W_att_r[d][k][a]
    } else {
      int p = pos - 32; int g = p >> 5; int m = j * 32 + (p & 31);
      x = Wl[((size_t)d * 768 + 512 + k) * H4 + (g << 8) + m];   // Wl h-part
    }
    v[kr] = x;
  }
  whs[idx] = make_uint2(packbf(v[0], v[1]), packbf(v[2], v[3]));
}

// ---- C[M][1280] = A[M][256] @ B[256][1280], fp32 ----------------------------
template <bool PERM>
__global__ __launch_bounds__(256) void sgemm(
    const float* __restrict__ A, const float* __restrict__ Bm,
    float* __restrict__ C)
{
  __shared__ float As[16][65];
  __shared__ float Bs[16][64];
  int tid = threadIdx.x;
  int tx = tid & 15, ty = tid >> 4;
  int col0 = blockIdx.x * 64, row0 = blockIdx.y * 64;
  float acc[4][4] = {};
  for (int kt = 0; kt < DD; kt += 16) {
    #pragma unroll
    for (int i = 0; i < 4; ++i) {
      int e = tid + i * 256;
      As[e & 15][e >> 4] = A[(size_t)(row0 + (e >> 4)) * DD + kt + (e & 15)];
      Bs[e >> 6][e & 63] = Bm[(size_t)(kt + (e >> 6)) * NC + col0 + (e & 63)];
    }
    __syncthreads();
    #pragma unroll
    for (int kk = 0; kk < 16; ++kk) {
      float a[4], bv[4];
      #pragma unroll
      for (int i = 0; i < 4; ++i) a[i] = As[kk][ty * 4 + i];
      #pragma unroll
      for (int jj = 0; jj < 4; ++jj) bv[jj] = Bs[kk][tx * 4 + jj];
      #pragma unroll
      for (int i = 0; i < 4; ++i)
        #pragma unroll
        for (int jj = 0; jj < 4; ++jj)
          acc[i][jj] = fmaf(a[i], bv[jj], acc[i][jj]);
    }
    __syncthreads();
  }
  #pragma unroll
  for (int i = 0; i < 4; ++i)
    #pragma unroll
    for (int jj = 0; jj < 4; ++jj) {
      int c = col0 + tx * 4 + jj;
      int cc = PERM ? perm_col(c) : c;
      C[(size_t)(row0 + ty * 4 + i) * NC + cc] = acc[i][jj];
    }
}

// ---- scan: 256 WGs x 256 threads --------------------------------------------
__global__ __launch_bounds__(256) void scan(
    const float* __restrict__ xpl,    // [NB*TP][NC] permuted cols
    const float* __restrict__ qv,     // [NB*TQ][NC] plain (this layer)
    const uint2* __restrict__ whs,    // this layer's 8 slices
    const float* __restrict__ wa,     // [256] (this layer)
    const float* __restrict__ bias_f, // [256]
    const float* __restrict__ bias_iog, // [768]
    const float* __restrict__ mask_p, // [NB*TP]
    const float* __restrict__ mask_q, // [NB*TQ]
    float* __restrict__ xch_s,        // [NB][8][64]
    float* __restrict__ xch_h,        // [NB][256]
    int* __restrict__ cnt,            // [NB][64]: [b][0]=cnt_s, [b][32]=cnt_h
    float* __restrict__ out)          // [NB*TP][256]
{
  const int bid = blockIdx.x;
  const int j = bid & 7, b = bid >> 3;
  const int tid = threadIdx.x;

  __shared__ __align__(16) float h_lds[DD];
  __shared__ float hw_att_s[32], xatt_s[32], wa_sh[32], c_sh[32];
  __shared__ float qWq_lds[TQL][33];
  __shared__ float Vl_lds[TQL][128];
  __shared__ float sc_part[4][TQL];
  __shared__ float al_s[TQL];
  __shared__ float pre_s[128], bias_sh[128];

  const float* qv_b = qv + (size_t)b * TQL * NC;
  const uint2* wsl = whs + (size_t)j * 64 * SC;
  float* xch_s_b = xch_s + b * (NS * TQL);
  float* xch_h_b = xch_h + b * DD;
  int* cnt_s_b = cnt + b * 64;
  int* cnt_h_b = cnt + b * 64 + 32;

  // ---- init: LDS-resident per-(b,j) data
  for (int i = tid; i < TQL * 32; i += 256) {
    int tq = i >> 5, a = i & 31;
    qWq_lds[tq][a] = qv_b[(size_t)tq * NC + (j << 5) + a];
  }
  for (int i = tid; i < TQL * 128; i += 256) {
    int tq = i >> 7, p = i & 127;
    int g = p >> 5, m = (j << 5) + (p & 31);
    Vl_lds[tq][p] = qv_b[(size_t)tq * NC + DD + (g << 8) + m];
  }
  if (tid < 32) {
    wa_sh[tid] = wa[(j << 5) + tid];
    c_sh[tid] = 0.f;
  }
  if (tid >= 32 && tid < 160) {
    int p = tid - 32; int g = p >> 5; int m = (j << 5) + (p & 31);
    bias_sh[p] = (g == 0) ? bias_f[m] : bias_iog[((g - 1) << 8) + m];
  }
  float mq = (tid < TQL) ? mask_q[b * TQL + tid] : 0.f;
  __syncthreads();

  for (int t = 0; t < TPL; ++t) {
    // ---- wait for h[t], load to LDS
    if (t > 0) {
      if (tid == 0) spin_ge(cnt_h_b, NS * t);
      __syncthreads();
      h_lds[tid] = aloadf(xch_h_b + tid);
    } else {
      h_lds[tid] = 0.f;
    }
    __syncthreads();

    const float* xs = xpl + ((size_t)b * TPL + t) * NC + j * SC;

    // ---- GEMV: hw for own 160 cols (bf16 slice, 4k per 8B load)
    float hw_t = 0.f;
    if (tid < SC) {
      const uint2* wp = wsl + tid;
      #pragma unroll 8
      for (int kq = 0; kq < 64; ++kq) {
        uint2 w = wp[kq * SC];
        float4 hv = *(const float4*)&h_lds[kq * 4];
        hw_t = fmaf(hv.x, bflo(w.x), hw_t);
        hw_t = fmaf(hv.y, bfhi(w.x), hw_t);
        hw_t = fmaf(hv.z, bflo(w.y), hw_t);
        hw_t = fmaf(hv.w, bfhi(w.y), hw_t);
      }
    }
    if (tid < 32) { hw_att_s[tid] = hw_t; xatt_s[tid] = xs[tid]; }
    __syncthreads();

    // ---- scores: s_part[tq] over own 32 att cols (thread = sub*64 + tq)
    {
      int tq = tid & 63, sub = tid >> 6;
      float part = 0.f;
      #pragma unroll
      for (int i = 0; i < 8; ++i) {
        int a = sub * 8 + i;
        part = fmaf(fast_tanh(qWq_lds[tq][a] + xatt_s[a] + hw_att_s[a]),
                    wa_sh[a], part);
      }
      sc_part[sub][tq] = part;
    }
    __syncthreads();
    if (tid < TQL) {
      float sp = sc_part[0][tid] + sc_part[1][tid] + sc_part[2][tid] + sc_part[3][tid];
      astoref(xch_s_b + j * TQL + tid, sp);
    }
    if (tid == 0) { radd(cnt_s_b); spin_ge(cnt_s_b, NS * (t + 1)); }
    __syncthreads();

    // ---- softmax (wave 0), alpha -> LDS
    if (tid < TQL) {
      float tot = 0.f;
      #pragma unroll
      for (int q = 0; q < NS; ++q) tot += aloadf(xch_s_b + q * TQL + tid);
      float v = (mq > 0.f) ? tot : -1e9f;
      float m = v;
      #pragma unroll
      for (int off = 32; off > 0; off >>= 1) m = fmaxf(m, __shfl_xor(m, off));
      float p = __expf(v - m);
      float su = p;
      #pragma unroll
      for (int off = 32; off > 0; off >>= 1) su += __shfl_xor(su, off);
      al_s[tid] = p * __builtin_amdgcn_rcpf(su);
    }
    __syncthreads();

    // ---- pre for own 128 gate cols (threads 32..159; hw_t still in reg)
    if (tid >= 32 && tid < SC) {
      int p = tid - 32;
      float acc = hw_t + xs[tid] + bias_sh[p];
      #pragma unroll 8
      for (int tq = 0; tq < TQL; ++tq)
        acc = fmaf(al_s[tq], Vl_lds[tq][p], acc);
      pre_s[p] = acc;
    }
    __syncthreads();

    // ---- gates + state for own 32 h-elems (threads 0..31)
    if (tid < 32) {
      float f  = pre_s[tid];
      float ii = pre_s[32 + tid];
      float oo = pre_s[64 + tid];
      float g  = pre_s[96 + tid];
      float mt = mask_p[b * TPL + t];
      int m = (j << 5) + tid;
      float c0 = c_sh[tid], h0 = h_lds[m];
      float c1 = fast_sigmoid(f) * c0 + fast_sigmoid(ii) * fast_tanh(g);
      c1 = c1 * mt + c0 * (1.f - mt);
      float h1 = fast_sigmoid(oo) * fast_tanh(c1);
      h1 = h1 * mt + h0 * (1.f - mt);
      c_sh[tid] = c1;
      astoref(xch_h_b + m, h1);
      out[((size_t)b * TPL + t) * DD + m] = h1;
    }
    if (tid == 0) radd(cnt_h_b);
    __syncthreads();
  }
}

// -----------------------------------------------------------------------------
extern "C" void kernel_launch(void* const* d_in, const int* in_sizes, int n_in,
                              void* d_out, int out_size, void* d_ws, size_t ws_size,
                              hipStream_t stream) {
  const float* input_p  = (const float*)d_in[0];
  const float* mask_p   = (const float*)d_in[1];
  const float* input_q  = (const float*)d_in[2];
  const float* mask_q   = (const float*)d_in[3];
  const float* W_att_p  = (const float*)d_in[4];
  const float* W_att_q  = (const float*)d_in[5];
  const float* W_att_r  = (const float*)d_in[6];
  const float* w_att    = (const float*)d_in[7];
  const float* W_lstm   = (const float*)d_in[8];
  const float* bias_f   = (const float*)d_in[9];
  const float* bias_iog = (const float*)d_in[10];
  float* out = (float*)d_out;
  float* ws  = (float*)d_ws;
  (void)ws_size; (void)in_sizes; (void)n_in; (void)out_size;

  const size_t SZ_XPL = (size_t)NB * TPL * NC;   // 20,971,520 f
  const size_t SZ_QV  = (size_t)NB * TQL * NC;   //  2,621,440 f per layer
  const size_t SZ_W   = (size_t)DD * NC;         //    327,680 f per layer
  const size_t SZ_WHS = (size_t)NS * 64 * SC;    //     81,920 uint2 per layer

  float* ws_xpl = ws;
  float* ws_qv  = ws_xpl + SZ_XPL;
  float* ws_wx  = ws_qv  + 2 * SZ_QV;
  float* ws_wqv = ws_wx  + 2 * SZ_W;
  float* ws_o0  = ws_wqv + 2 * SZ_W;
  uint2* ws_whs = (uint2*)(ws_o0 + (size_t)NB * TPL * DD);
  float* ws_xs  = (float*)(ws_whs + 2 * SZ_WHS);   // xch_s [NB][8][64]
  float* ws_xh  = ws_xs + NB * NS * TQL;           // xch_h [NB][256]
  int*   ws_cnt = (int*)(ws_xh + NB * DD);         // [NB][64]

  dim3 gpack((DD * NC + 255) / 256, 2);
  pack_weights<<<gpack, 256, 0, stream>>>(W_att_p, W_att_q, W_lstm, ws_wx, ws_wqv);
  pack_whs<<<(2 * NS * 64 * SC + 255) / 256, 256, 0, stream>>>(W_att_r, W_lstm, ws_whs);

  for (int d = 0; d < 2; ++d) {
    dim3 g(NC / 64, (NB * TQL) / 64);
    sgemm<false><<<g, 256, 0, stream>>>(input_q, ws_wqv + d * SZ_W, ws_qv + d * SZ_QV);
  }

  // layer 0
  {
    dim3 g(NC / 64, (NB * TPL) / 64);
    sgemm<true><<<g, 256, 0, stream>>>(input_p, ws_wx, ws_xpl);
    hipMemsetAsync(ws_cnt, 0, NB * 64 * sizeof(int), stream);
    scan<<<NB * NS, 256, 0, stream>>>(ws_xpl, ws_qv, ws_whs,
                                      w_att, bias_f, bias_iog, mask_p, mask_q,
                                      ws_xs, ws_xh, ws_cnt, ws_o0);
  }
  // layer 1
  {
    dim3 g(NC / 64, (NB * TPL) / 64);
    sgemm<true><<<g, 256, 0, stream>>>(ws_o0, ws_wx + SZ_W, ws_xpl);
    hipMemsetAsync(ws_cnt, 0, NB * 64 * sizeof(int), stream);
    scan<<<NB * NS, 256, 0, stream>>>(ws_xpl, ws_qv + SZ_QV, ws_whs + SZ_WHS,
                                      w_att + DD, bias_f + DD, bias_iog + 3 * DD,
                                      mask_p, mask_q, ws_xs, ws_xh, ws_cnt, out);
  }
}